// Round 17
// baseline (230.784 us; speedup 1.0000x reference)
//
#include <hip/hip_runtime.h>

// ---------------------------------------------------------------------------
// VQPromptBlock round 16:
//  - fused_layer: round-15 form (v5 + XCD swizzle) — best measured, untouched.
//  - Tail fusion: dist now writes q directly (it holds the tokens already);
//    redo patches the few margin-flagged rows it corrects; finalize slims to
//    wf/diff only (64-thread blocks). Removes a full 33.5 MB q write pass +
//    codebook re-gather.
// ---------------------------------------------------------------------------

typedef __attribute__((ext_vector_type(8))) short short8;
typedef __attribute__((ext_vector_type(16))) float f32x16;
typedef __attribute__((ext_vector_type(8))) _Float16 half8;
typedef __attribute__((ext_vector_type(2))) _Float16 half2_t;
typedef unsigned short ushort_t;
typedef unsigned long long u64;

// ws float offsets
#define WS_QA    0           // q ping bf16 [65536][256] = 8388608 fl
#define WS_QB    8388608     // q pong bf16
#define WS_ET    16777216    // embedT bf16 [512][256] = 65536 fl
#define WS_EN    16842752    // enorm fp32 [512]
#define WS_EPK   16843264    // epk f16 [ks16][at16][64][8] = 65536 fl
#define WS_W1PK  16908800    // w1 frag pack bf16 = 221184 fl
#define WS_W2PK  17129984    // w2 frag pack bf16 = 24576 fl
#define WS_DIFF  17154560    // 1 fl
#define WS_TOK   17154568    // 65536 int
#define WS_DST   17220104    // 65536 fl
#define WS_FN    17285640    // 65536 fl
#define WS_WL    17351176    // 1 count + 65536 entries (int)

#define MARGIN 0.12f

__device__ inline ushort_t f2bf(float f) {
  unsigned u = __float_as_uint(f);
  return (ushort_t)((u + 0x7fffu + ((u >> 16) & 1u)) >> 16);
}
__device__ inline float bf2f(ushort_t h) { return __uint_as_float(((unsigned)h) << 16); }
union HU { _Float16 h; ushort_t u; };
union S8H { short8 s; half8 h; half2_t h2[4]; };

// ---------------------------------------------------------------------------
// prep (round 9 verbatim)
// ---------------------------------------------------------------------------
__global__ __launch_bounds__(256) void prep_kernel(
    const float* __restrict__ embed, const float* __restrict__ w1,
    const float* __restrict__ w2, float* __restrict__ ws, float* __restrict__ wf) {
  int i = blockIdx.x * 256 + threadIdx.x;
  if (i < 131072) {             // embedT bf16 [t][c]
    int t = i >> 8, c = i & 255;
    ((ushort_t*)(ws + WS_ET))[i] = f2bf(embed[c * 512 + t]);
  }
  if (i < 512) {                // enorm fp32 (exact)
    float s = 0.f;
    for (int c = 0; c < 256; ++c) { float v = embed[c * 512 + i]; s += v * v; }
    ws[WS_EN + i] = s;
  }
  if (i < 131072) {             // epk f16: [ks][at][lane][8]
    int j = i & 7, lane = (i >> 3) & 63, at = (i >> 9) & 15, ks = i >> 13;
    int code = at * 32 + (lane & 31);
    int c = ks * 16 + (lane >> 5) * 8 + j;
    HU cv; cv.h = (_Float16)embed[c * 512 + code];
    ((ushort_t*)(ws + WS_EPK))[i] = cv.u;
  }
  if (i < 442368) {             // w1pk bf16: [l][tap][k16][of2][lane][8]
    int j = i & 7; int lane = (i >> 3) & 63; int of = (i >> 9) & 1;
    int k16 = (i >> 10) & 15; int rest = i >> 14;
    int tap = rest % 9; int layer = rest / 9;
    int oc = of * 32 + (lane & 31);
    int c = k16 * 16 + (lane >> 5) * 8 + j;
    ((ushort_t*)(ws + WS_W1PK))[i] = f2bf(w1[((layer * 64 + oc) * 256 + c) * 9 + tap]);
  }
  if (i < 49152) {              // w2pk bf16 [l][ks4][at8][lane][8]
    int j = i & 7, lane = (i >> 3) & 63, at = (i >> 9) & 7, ks = (i >> 12) & 3, l = i >> 14;
    int co = at * 32 + (lane & 31), cb = ks * 16 + (lane >> 5) * 8 + j;
    ((ushort_t*)(ws + WS_W2PK))[i] = f2bf(w2[(l * 256 + co) * 64 + cb]);
  }
  if (i < 8192) wf[i] = 0.f;
  if (i == 0) { ws[WS_DIFF] = 0.f; ((int*)(ws + WS_WL))[0] = 0; }
}

// ---------------------------------------------------------------------------
// dist: r9 GEMM + reduction, NOW ALSO writes q rows (tokens are in LDS).
// ---------------------------------------------------------------------------
__global__ __launch_bounds__(512, 4) void dist_kernel(
    const float* __restrict__ input, const half8* __restrict__ epk,
    const float* __restrict__ enorm, const ushort_t* __restrict__ embedT,
    int* __restrict__ tok, float* __restrict__ dst, float* __restrict__ fnv,
    int* __restrict__ wl, ushort_t* __restrict__ qout) {
  __shared__ __align__(16) ushort_t sfp[2048 * 8];   // 32 KB
  __shared__ float senorm[512];
  __shared__ float trim1[512], trim2[512];           // [64 pos][8 wave]
  __shared__ int   trii[512];
  __shared__ int   stok[64];

  int blk = blockIdx.x, b = blk >> 6, hw0 = (blk & 63) << 6;
  int tid = threadIdx.x, lane = tid & 63, wave = tid >> 6;
  senorm[tid] = enorm[tid];

  {
    int cg = tid >> 3, sub = tid & 7;
    int ks_s = cg >> 2, hi_s = (cg >> 1) & 1, jq = cg & 1;
    const float* src0 = input + ((size_t)(b * 256 + cg * 4)) * 4096 + hw0 + sub * 8;
    float vv[4][8];
#pragma unroll
    for (int m = 0; m < 4; ++m) {
      const float4* s4 = (const float4*)(src0 + (size_t)m * 4096);
      float4 aa = s4[0], bb = s4[1];
      vv[m][0] = aa.x; vv[m][1] = aa.y; vv[m][2] = aa.z; vv[m][3] = aa.w;
      vv[m][4] = bb.x; vv[m][5] = bb.y; vv[m][6] = bb.z; vv[m][7] = bb.w;
    }
    u64* sfp64 = (u64*)sfp;
#pragma unroll
    for (int i = 0; i < 8; ++i) {
      int pl = sub * 8 + i;
      int bt = pl >> 5, lw = (pl & 31) + 32 * hi_s;
      u64 pk = 0;
#pragma unroll
      for (int m = 0; m < 4; ++m) {
        HU cv; cv.h = (_Float16)vv[m][i];
        pk |= ((u64)cv.u) << (16 * m);
      }
      sfp64[((bt * 16 + ks_s) * 64 + lw) * 2 + jq] = pk;
    }
  }
  __syncthreads();

  f32x16 acc[2][2];
#pragma unroll
  for (int bt = 0; bt < 2; ++bt)
#pragma unroll
    for (int a = 0; a < 2; ++a)
#pragma unroll
      for (int r = 0; r < 16; ++r) acc[bt][a][r] = 0.f;

  const short8* sfp8 = (const short8*)sfp;
  float fnp0 = 0.f, fnp1 = 0.f;
#pragma unroll 2
  for (int ks = 0; ks < 16; ++ks) {
    S8H u0, u1;
    u0.s = sfp8[ks * 64 + lane];
    u1.s = sfp8[(16 + ks) * 64 + lane];
#if __has_builtin(__builtin_amdgcn_fdot2)
#pragma unroll
    for (int k = 0; k < 4; ++k) {
      fnp0 = __builtin_amdgcn_fdot2(u0.h2[k], u0.h2[k], fnp0, false);
      fnp1 = __builtin_amdgcn_fdot2(u1.h2[k], u1.h2[k], fnp1, false);
    }
#else
#pragma unroll
    for (int k = 0; k < 8; ++k) {
      float v0 = (float)u0.h[k], v1 = (float)u1.h[k];
      fnp0 += v0 * v0; fnp1 += v1 * v1;
    }
#endif
#pragma unroll
    for (int a = 0; a < 2; ++a) {
      half8 ah = epk[(ks * 16 + wave * 2 + a) * 64 + lane];
      acc[0][a] = __builtin_amdgcn_mfma_f32_32x32x16_f16(ah, u0.h, acc[0][a], 0, 0, 0);
      acc[1][a] = __builtin_amdgcn_mfma_f32_32x32x16_f16(ah, u1.h, acc[1][a], 0, 0, 0);
    }
  }
  fnp0 += __shfl_xor(fnp0, 32, 64);
  fnp1 += __shfl_xor(fnp1, 32, 64);

  int hi5 = lane >> 5;
#pragma unroll
  for (int bt = 0; bt < 2; ++bt) {
    float m1 = 3.4e38f, m2 = 3.4e38f; int i1 = 0;
#pragma unroll
    for (int a = 0; a < 2; ++a)
#pragma unroll
      for (int r = 0; r < 16; ++r) {
        int code = (wave * 2 + a) * 32 + (r & 3) + 8 * (r >> 2) + 4 * hi5;
        float v = senorm[code] - 2.0f * acc[bt][a][r];
        if (v < m1) { m2 = m1; m1 = v; i1 = code; }
        else if (v < m2) m2 = v;
      }
    float o1 = __shfl_xor(m1, 32, 64);
    float o2 = __shfl_xor(m2, 32, 64);
    int   oi = __shfl_xor(i1, 32, 64);
    float n2 = fminf(fmaxf(m1, o1), fminf(m2, o2));
    float n1 = fminf(m1, o1);
    int   ni = (o1 < m1) ? oi : i1;
    if (lane < 32) {
      int p = bt * 32 + lane;
      trim1[p * 8 + wave] = n1; trim2[p * 8 + wave] = n2; trii[p * 8 + wave] = ni;
    }
  }
  __syncthreads();

  if (wave == 0) {
    int p = lane;
    float m1 = trim1[p * 8], m2 = trim2[p * 8]; int i1 = trii[p * 8];
#pragma unroll
    for (int w = 1; w < 8; ++w) {
      float a1 = trim1[p * 8 + w], a2 = trim2[p * 8 + w]; int ai = trii[p * 8 + w];
      float n2 = fminf(fmaxf(m1, a1), fminf(m2, a2));
      if (a1 < m1) { m1 = a1; i1 = ai; }
      m2 = n2;
    }
    float myfn = (lane < 32) ? fnp0 : fnp1;
    int gpos = blk * 64 + p;
    stok[p] = i1;
    tok[gpos] = i1;
    dst[gpos] = myfn + m1;
    fnv[gpos] = myfn;
    bool flag = (m2 - m1 < MARGIN);
    u64 mk = __ballot(flag);
    int base = 0;
    if (lane == 0 && mk) base = atomicAdd(wl, (int)__popcll(mk));
    base = __shfl(base, 0, 64);
    if (flag) {
      int off = (int)__popcll(mk & ((1ull << lane) - 1ull));
      wl[1 + base + off] = gpos;
    }
  }
  __syncthreads();

  // ---- q gather-write: 8 waves x 8 rows (redo patches flagged rows later) ----
#pragma unroll 1
  for (int j = 0; j < 8; ++j) {
    int p = wave * 8 + j;
    int t0 = __builtin_amdgcn_readfirstlane(stok[p]);
    const u64* src = (const u64*)(embedT + (size_t)t0 * 256);
    u64* dstp = (u64*)(qout + ((size_t)(blk * 64 + p)) * 256);
    dstp[lane] = src[lane];
  }
}

// ---------------------------------------------------------------------------
// redo: exact fp32 recompute for flagged positions; patches tok/dst AND the
// q row dist wrote (64 u64 per row).
// ---------------------------------------------------------------------------
__global__ __launch_bounds__(256) void redo_kernel(
    const float* __restrict__ input, const float* __restrict__ embed,
    const float* __restrict__ enorm, const int* __restrict__ wl,
    int* __restrict__ tok, float* __restrict__ dst, const float* __restrict__ fnv,
    const ushort_t* __restrict__ embedT, ushort_t* __restrict__ qout) {
  __shared__ float sf[256], rv[256];
  __shared__ int   ri[256];
  int n = wl[0];
  int tid = threadIdx.x;
  for (int e = blockIdx.x; e < n; e += gridDim.x) {
    int gpos = wl[1 + e];
    int b = gpos >> 12, hw = gpos & 4095;
    sf[tid] = input[((size_t)(b * 256 + tid)) * 4096 + hw];
    __syncthreads();
    float d0 = 0.f, d1 = 0.f;
#pragma unroll 4
    for (int c = 0; c < 256; ++c) {
      float fv = sf[c];
      d0 += fv * embed[c * 512 + tid];
      d1 += fv * embed[c * 512 + 256 + tid];
    }
    float v0 = enorm[tid] - 2.f * d0;
    float v1 = enorm[256 + tid] - 2.f * d1;
    float bv; int bi;
    if (v1 < v0) { bv = v1; bi = 256 + tid; } else { bv = v0; bi = tid; }
    rv[tid] = bv; ri[tid] = bi;
    __syncthreads();
    for (int s = 128; s > 0; s >>= 1) {
      if (tid < s) {
        float ov = rv[tid + s]; int oi2 = ri[tid + s];
        if (ov < rv[tid] || (ov == rv[tid] && oi2 < ri[tid])) { rv[tid] = ov; ri[tid] = oi2; }
      }
      __syncthreads();
    }
    if (tid == 0) { tok[gpos] = ri[0]; dst[gpos] = fnv[gpos] + rv[0]; }
    // patch the q row with the corrected token
    if (tid < 64) {
      const u64* src = (const u64*)(embedT + (size_t)ri[0] * 256);
      u64* dstp = (u64*)(qout + (size_t)gpos * 256);
      dstp[tid] = src[tid];
    }
    __syncthreads();
  }
}

// ---------------------------------------------------------------------------
// finalize (slim): wordfreq atomics + diff reduction only. 1024 x 64 thr.
// ---------------------------------------------------------------------------
__global__ __launch_bounds__(64) void finalize_kernel(
    const int* __restrict__ tok, const float* __restrict__ dst,
    float* __restrict__ wf, float* __restrict__ diffp) {
  int gbase = blockIdx.x * 64;
  int lane = threadIdx.x;
  int b = gbase >> 12;
  int t = tok[gbase + lane];
  atomicAdd(&wf[b * 512 + t], 1.0f / 4096.0f);
  float d = dst[gbase + lane];
#pragma unroll
  for (int off = 32; off >= 1; off >>= 1) d += __shfl_down(d, off, 64);
  if (lane == 0) atomicAdd(diffp, d);
}

// ---------------------------------------------------------------------------
// fused residual layer v5 + T1 XCD swizzle (round 15 verbatim — best).
// ---------------------------------------------------------------------------
__global__ __launch_bounds__(512, 4) void fused_layer(
    const ushort_t* __restrict__ qin, ushort_t* __restrict__ qout,
    const ushort_t* __restrict__ w1pk, const float* __restrict__ b1,
    const ushort_t* __restrict__ w2pk, const float* __restrict__ b2, int l) {
  __shared__ __align__(16) char arena[38912];
  ushort_t* hbuf   = (ushort_t*)arena;             // [64][76] = 9728 B
  float*    sb2    = (float*)(arena + 9728);       // 256 fl
  short8*   stg    = (short8*)(arena + 10752);     // 2 x 880 units (GEMM1)
  float*    red    = (float*)(arena + 10752);      // 4096 fl (K-reduce overlay)
  ushort_t* qstage = (ushort_t*)(arena + 10752);   // [64][136] (GEMM2 overlay)

  // T1: bijective XCD-chunked swizzle (nwg = 1024, 8 XCDs, 128 blocks/XCD)
  int raw = blockIdx.x;
  int blk = (raw & 7) * 128 + (raw >> 3);

  int b = blk >> 6; int t = blk & 63;
  int ty0 = (t >> 3) << 3;
  int tx0 = (t & 7) << 3;
  int tid = threadIdx.x, lane = tid & 63, w = tid >> 6;
  int pt = w & 1, ot = (w >> 1) & 1, kh = w >> 2;
  int l31 = lane & 31, kb5 = lane >> 5;

  if (tid < 256) sb2[tid] = b2[l * 256 + tid];

  const short8* wp  = (const short8*)w1pk + (size_t)l * 18432;
  const short8* w2p = (const short8*)w2pk;

  short8 sreg[2];
  auto loadch = [&](int cs) {
#pragma unroll
    for (int s = 0; s < 2; ++s) {
      int u = s * 512 + tid;
      if (u < 800) {
        int cg = u & 7; int pix = u >> 3; int y = pix / 10; int x = pix - y * 10;
        int sy = ty0 + y - 1, sx = tx0 + x - 1;
        if (sy >= 0 && sy < 64 && sx >= 0 && sx < 64) {
          sreg[s] = *(const short8*)(qin + ((size_t)(b * 4096 + sy * 64 + sx)) * 256 + cs * 64 + cg * 8);
        } else {
          short8 z;
#pragma unroll
          for (int k2 = 0; k2 < 8; ++k2) z[k2] = 0;
          sreg[s] = z;
        }
      }
    }
  };
  auto writech = [&](int buf) {
#pragma unroll
    for (int s = 0; s < 2; ++s) {
      int u = s * 512 + tid;
      if (u < 800) {
        int cg = u & 7; int pix = u >> 3; int y = pix / 10; int x = pix - y * 10;
        short8 sv = sreg[s];
#pragma unroll
        for (int k2 = 0; k2 < 8; ++k2) if (sv[k2] < 0) sv[k2] = 0;   // bf16 relu
        stg[buf * 880 + (y * 8 + cg) * 11 + x] = sv;
      }
    }
  };

  // ---- GEMM1: 4 chunks of 64 ch, K-split across kh ----
  f32x16 acc;
#pragma unroll
  for (int r = 0; r < 16; ++r) acc[r] = 0.f;

  int py0 = pt * 4 + (l31 >> 3);
  int px0 = lane & 7;

  loadch(0);
  writech(0);
#pragma unroll 1
  for (int cs = 0; cs < 4; ++cs) {
    __syncthreads();                      // buf[cs&1] writes visible
    if (cs < 3) loadch(cs + 1);           // issue loads; hidden by MFMAs
    int buf = cs & 1;
#pragma unroll 1
    for (int dy = 0; dy < 3; ++dy) {
#pragma unroll 1
      for (int dx = 0; dx < 3; ++dx) {
        int tap = dy * 3 + dx;
#pragma unroll
        for (int ks2 = 0; ks2 < 2; ++ks2) {
          int kk = kh * 2 + ks2;          // k16 within chunk
          short8 A = stg[buf * 880 + ((py0 + dy) * 8 + kk * 2 + kb5) * 11 + px0 + dx];
          short8 B = wp[(tap * 16 + cs * 4 + kk) * 128 + ot * 64 + lane];
          acc = __builtin_amdgcn_mfma_f32_32x32x16_bf16(A, B, acc, 0, 0, 0);
        }
      }
    }
    if (cs < 3) writech((cs + 1) & 1);    // write late
  }
  __syncthreads();

  // ---- K-reduce: kh=1 partials through LDS, kh=0 combines -> hbuf ----
  if (kh == 1) {
    float4* d = (float4*)(red + (w & 3) * 1024 + lane * 16);
#pragma unroll
    for (int r4 = 0; r4 < 4; ++r4) {
      float4 v; v.x = acc[r4 * 4]; v.y = acc[r4 * 4 + 1];
      v.z = acc[r4 * 4 + 2]; v.w = acc[r4 * 4 + 3];
      d[r4] = v;
    }
  }
  __syncthreads();
  if (kh == 0) {
    const float* s = red + (w & 3) * 1024 + lane * 16;
    int oc = ot * 32 + l31;
    float bb = b1[l * 64 + oc];
#pragma unroll
    for (int r = 0; r < 16; ++r) {
      int row = (r & 3) + 8 * (r >> 2) + 4 * kb5;
      hbuf[(pt * 32 + row) * 76 + oc] = f2bf(fmaxf(acc[r] + s[r] + bb, 0.f));
    }
  }
  __syncthreads();

  // ---- GEMM2: wave = (pt2, coq); 2 co-halves through qstage ----
  int pt2 = w & 1, coq = w >> 1;          // coq 0..3
#pragma unroll 1
  for (int ch = 0; ch < 2; ++ch) {
    short8 qv[2];
#pragma unroll
    for (int it = 0; it < 2; ++it) {
      int u = it * 512 + tid;
      int p = u >> 4, c8 = u & 15;
      int gy = ty0 + (p >> 3), gx = tx0 + (p & 7);
      qv[it] = *(const short8*)(qin + ((size_t)(b * 4096 + gy * 64 + gx)) * 256 + ch * 128 + c8 * 8);
    }

    f32x16 acc2;
#pragma unroll
    for (int r = 0; r < 16; ++r) acc2[r] = 0.f;
#pragma unroll
    for (int ks = 0; ks < 4; ++ks) {
      short8 A = *(const short8*)(hbuf + (pt2 * 32 + l31) * 76 + ks * 16 + kb5 * 8);
      short8 B = w2p[((l * 4 + ks) * 8 + ch * 4 + coq) * 64 + lane];
      acc2 = __builtin_amdgcn_mfma_f32_32x32x16_bf16(A, B, acc2, 0, 0, 0);
    }
    {
      int cc = coq * 32 + l31;
      float bb2 = sb2[ch * 128 + cc];
#pragma unroll
      for (int r = 0; r < 16; ++r) {
        int row = (r & 3) + 8 * (r >> 2) + 4 * kb5;
        qstage[(pt2 * 32 + row) * 136 + cc] = f2bf(acc2[r] + bb2);
      }
    }
    __syncthreads();
#pragma unroll
    for (int it = 0; it < 2; ++it) {
      int u = it * 512 + tid;
      int p = u >> 4, c8 = u & 15;
      short8 hv = *(const short8*)(qstage + p * 136 + c8 * 8);
      int gy = ty0 + (p >> 3), gx = tx0 + (p & 7);
      size_t gidx = ((size_t)(b * 4096 + gy * 64 + gx)) * 256 + ch * 128 + c8 * 8;
      short8 ov;
#pragma unroll
      for (int k2 = 0; k2 < 8; ++k2)
        ov[k2] = (short)f2bf(bf2f((ushort_t)qv[it][k2]) + bf2f((ushort_t)hv[k2]));
      *(short8*)(qout + gidx) = ov;
    }
    __syncthreads();
  }
}

// ---------------------------------------------------------------------------
// final 1x1 head (unchanged)
// ---------------------------------------------------------------------------
__global__ __launch_bounds__(256) void final_kernel(
    const ushort_t* __restrict__ qbuf, const float* __restrict__ ow,
    const float* __restrict__ ob, float* __restrict__ out,
    const float* __restrict__ ws) {
  int t = blockIdx.x * 256 + threadIdx.x;
  int pos = t >> 4, c16 = t & 15;
  const ushort_t* qp = qbuf + (size_t)pos * 256 + c16 * 16;
  short8 v0 = *(const short8*)qp;
  short8 v1 = *(const short8*)(qp + 8);
  float a0 = 0.f, a1 = 0.f, a2 = 0.f;
#pragma unroll
  for (int k = 0; k < 16; ++k) {
    float f = bf2f((ushort_t)(k < 8 ? v0[k] : v1[k - 8]));
    int c = c16 * 16 + k;
    a0 += f * ow[c];
    a1 += f * ow[256 + c];
    a2 += f * ow[512 + c];
  }
#pragma unroll
  for (int off = 1; off < 16; off <<= 1) {
    a0 += __shfl_xor(a0, off, 64);
    a1 += __shfl_xor(a1, off, 64);
    a2 += __shfl_xor(a2, off, 64);
  }
  if (c16 == 0) {
    int b = pos >> 12, hw = pos & 4095;
    out[(b * 3 + 0) * 4096 + hw] = a0 + ob[0];
    out[(b * 3 + 1) * 4096 + hw] = a1 + ob[1];
    out[(b * 3 + 2) * 4096 + hw] = a2 + ob[2];
  }
  if (t == 0) out[196608] = ws[WS_DIFF] * (1.0f / 16777216.0f);
}

// ---------------------------------------------------------------------------
extern "C" void kernel_launch(void* const* d_in, const int* in_sizes, int n_in,
                              void* d_out, int out_size, void* d_ws, size_t ws_size,
                              hipStream_t stream) {
  (void)in_sizes; (void)n_in; (void)out_size; (void)ws_size;
  const float* input = (const float*)d_in[0];
  const float* embed = (const float*)d_in[1];
  const float* b1 = (const float*)d_in[3];
  const float* b2 = (const float*)d_in[5];
  const float* ow = (const float*)d_in[6];
  const float* ob = (const float*)d_in[7];
  float* ws = (float*)d_ws;
  float* out = (float*)d_out;
  float* wf = out + 196609;

  ushort_t* qA = (ushort_t*)(ws + WS_QA);
  ushort_t* qB = (ushort_t*)(ws + WS_QB);
  const ushort_t* et = (const ushort_t*)(ws + WS_ET);
  const half8* epk = (const half8*)(ws + WS_EPK);
  const ushort_t* w1pk = (const ushort_t*)(ws + WS_W1PK);
  const ushort_t* w2pk = (const ushort_t*)(ws + WS_W2PK);
  int*   tok = (int*)(ws + WS_TOK);
  float* dst = ws + WS_DST;
  float* fnv = ws + WS_FN;
  int*   wl  = (int*)(ws + WS_WL);

  hipLaunchKernelGGL(prep_kernel, dim3(1728), dim3(256), 0, stream,
                     embed, (const float*)d_in[2], (const float*)d_in[4], ws, wf);
  hipLaunchKernelGGL(dist_kernel, dim3(1024), dim3(512), 0, stream,
                     input, epk, ws + WS_EN, et, tok, dst, fnv, wl, qA);
  hipLaunchKernelGGL(redo_kernel, dim3(1024), dim3(256), 0, stream,
                     input, embed, ws + WS_EN, wl, tok, dst, fnv, et, qA);
  hipLaunchKernelGGL(finalize_kernel, dim3(1024), dim3(64), 0, stream,
                     tok, dst, wf, ws + WS_DIFF);
  hipLaunchKernelGGL(fused_layer, dim3(1024), dim3(512), 0, stream,
                     qA, qB, w1pk, b1, w2pk, b2, 0);
  hipLaunchKernelGGL(fused_layer, dim3(1024), dim3(512), 0, stream,
                     qB, qA, w1pk, b1, w2pk, b2, 1);
  hipLaunchKernelGGL(fused_layer, dim3(1024), dim3(512), 0, stream,
                     qA, qB, w1pk, b1, w2pk, b2, 2);
  hipLaunchKernelGGL(final_kernel, dim3(4096), dim3(256), 0, stream,
                     qB, ow, ob, out, ws);
}

// Round 18
// 220.909 us; speedup vs baseline: 1.0447x; 1.0447x over previous
//
#include <hip/hip_runtime.h>

// ---------------------------------------------------------------------------
// VQPromptBlock round 17:
//  - qA never materialized: layer 0 gathers activations straight from the
//    L2-resident codebook (embedT) via tok (staged 100 ints/block). Deletes
//    the 33.5 MB q write + 67 MB of qA HBM reads.
//  - dist / redo: back to lean round-9 forms. finalize: slim wf/diff (r16).
//  - fused_layer (layers 1,2): round-15 v5 + XCD swizzle, untouched.
//  - fused_layer0: v5 + swizzle with token-indirected staging & residual.
// ---------------------------------------------------------------------------

typedef __attribute__((ext_vector_type(8))) short short8;
typedef __attribute__((ext_vector_type(16))) float f32x16;
typedef __attribute__((ext_vector_type(8))) _Float16 half8;
typedef __attribute__((ext_vector_type(2))) _Float16 half2_t;
typedef unsigned short ushort_t;
typedef unsigned long long u64;

// ws float offsets
#define WS_QA    0           // q ping bf16 (layer0 OUTPUT only now)
#define WS_QB    8388608     // q pong bf16
#define WS_ET    16777216    // embedT bf16 [512][256] = 65536 fl
#define WS_EN    16842752    // enorm fp32 [512]
#define WS_EPK   16843264    // epk f16 [ks16][at16][64][8] = 65536 fl
#define WS_W1PK  16908800    // w1 frag pack bf16 = 221184 fl
#define WS_W2PK  17129984    // w2 frag pack bf16 = 24576 fl
#define WS_DIFF  17154560    // 1 fl
#define WS_TOK   17154568    // 65536 int
#define WS_DST   17220104    // 65536 fl
#define WS_FN    17285640    // 65536 fl
#define WS_WL    17351176    // 1 count + 65536 entries (int)

#define MARGIN 0.12f

__device__ inline ushort_t f2bf(float f) {
  unsigned u = __float_as_uint(f);
  return (ushort_t)((u + 0x7fffu + ((u >> 16) & 1u)) >> 16);
}
__device__ inline float bf2f(ushort_t h) { return __uint_as_float(((unsigned)h) << 16); }
union HU { _Float16 h; ushort_t u; };
union S8H { short8 s; half8 h; half2_t h2[4]; };

// ---------------------------------------------------------------------------
// prep (round 9 verbatim)
// ---------------------------------------------------------------------------
__global__ __launch_bounds__(256) void prep_kernel(
    const float* __restrict__ embed, const float* __restrict__ w1,
    const float* __restrict__ w2, float* __restrict__ ws, float* __restrict__ wf) {
  int i = blockIdx.x * 256 + threadIdx.x;
  if (i < 131072) {             // embedT bf16 [t][c]
    int t = i >> 8, c = i & 255;
    ((ushort_t*)(ws + WS_ET))[i] = f2bf(embed[c * 512 + t]);
  }
  if (i < 512) {                // enorm fp32 (exact)
    float s = 0.f;
    for (int c = 0; c < 256; ++c) { float v = embed[c * 512 + i]; s += v * v; }
    ws[WS_EN + i] = s;
  }
  if (i < 131072) {             // epk f16: [ks][at][lane][8]
    int j = i & 7, lane = (i >> 3) & 63, at = (i >> 9) & 15, ks = i >> 13;
    int code = at * 32 + (lane & 31);
    int c = ks * 16 + (lane >> 5) * 8 + j;
    HU cv; cv.h = (_Float16)embed[c * 512 + code];
    ((ushort_t*)(ws + WS_EPK))[i] = cv.u;
  }
  if (i < 442368) {             // w1pk bf16: [l][tap][k16][of2][lane][8]
    int j = i & 7; int lane = (i >> 3) & 63; int of = (i >> 9) & 1;
    int k16 = (i >> 10) & 15; int rest = i >> 14;
    int tap = rest % 9; int layer = rest / 9;
    int oc = of * 32 + (lane & 31);
    int c = k16 * 16 + (lane >> 5) * 8 + j;
    ((ushort_t*)(ws + WS_W1PK))[i] = f2bf(w1[((layer * 64 + oc) * 256 + c) * 9 + tap]);
  }
  if (i < 49152) {              // w2pk bf16 [l][ks4][at8][lane][8]
    int j = i & 7, lane = (i >> 3) & 63, at = (i >> 9) & 7, ks = (i >> 12) & 3, l = i >> 14;
    int co = at * 32 + (lane & 31), cb = ks * 16 + (lane >> 5) * 8 + j;
    ((ushort_t*)(ws + WS_W2PK))[i] = f2bf(w2[(l * 256 + co) * 64 + cb]);
  }
  if (i < 8192) wf[i] = 0.f;
  if (i == 0) { ws[WS_DIFF] = 0.f; ((int*)(ws + WS_WL))[0] = 0; }
}

// ---------------------------------------------------------------------------
// dist (round 9 verbatim — no q write)
// ---------------------------------------------------------------------------
__global__ __launch_bounds__(512, 4) void dist_kernel(
    const float* __restrict__ input, const half8* __restrict__ epk,
    const float* __restrict__ enorm, int* __restrict__ tok,
    float* __restrict__ dst, float* __restrict__ fnv, int* __restrict__ wl) {
  __shared__ __align__(16) ushort_t sfp[2048 * 8];   // 32 KB
  __shared__ float senorm[512];
  __shared__ float trim1[512], trim2[512];           // [64 pos][8 wave]
  __shared__ int   trii[512];

  int blk = blockIdx.x, b = blk >> 6, hw0 = (blk & 63) << 6;
  int tid = threadIdx.x, lane = tid & 63, wave = tid >> 6;
  senorm[tid] = enorm[tid];

  {
    int cg = tid >> 3, sub = tid & 7;
    int ks_s = cg >> 2, hi_s = (cg >> 1) & 1, jq = cg & 1;
    const float* src0 = input + ((size_t)(b * 256 + cg * 4)) * 4096 + hw0 + sub * 8;
    float vv[4][8];
#pragma unroll
    for (int m = 0; m < 4; ++m) {
      const float4* s4 = (const float4*)(src0 + (size_t)m * 4096);
      float4 aa = s4[0], bb = s4[1];
      vv[m][0] = aa.x; vv[m][1] = aa.y; vv[m][2] = aa.z; vv[m][3] = aa.w;
      vv[m][4] = bb.x; vv[m][5] = bb.y; vv[m][6] = bb.z; vv[m][7] = bb.w;
    }
    u64* sfp64 = (u64*)sfp;
#pragma unroll
    for (int i = 0; i < 8; ++i) {
      int pl = sub * 8 + i;
      int bt = pl >> 5, lw = (pl & 31) + 32 * hi_s;
      u64 pk = 0;
#pragma unroll
      for (int m = 0; m < 4; ++m) {
        HU cv; cv.h = (_Float16)vv[m][i];
        pk |= ((u64)cv.u) << (16 * m);
      }
      sfp64[((bt * 16 + ks_s) * 64 + lw) * 2 + jq] = pk;
    }
  }
  __syncthreads();

  f32x16 acc[2][2];
#pragma unroll
  for (int bt = 0; bt < 2; ++bt)
#pragma unroll
    for (int a = 0; a < 2; ++a)
#pragma unroll
      for (int r = 0; r < 16; ++r) acc[bt][a][r] = 0.f;

  const short8* sfp8 = (const short8*)sfp;
  float fnp0 = 0.f, fnp1 = 0.f;
#pragma unroll 2
  for (int ks = 0; ks < 16; ++ks) {
    S8H u0, u1;
    u0.s = sfp8[ks * 64 + lane];
    u1.s = sfp8[(16 + ks) * 64 + lane];
#if __has_builtin(__builtin_amdgcn_fdot2)
#pragma unroll
    for (int k = 0; k < 4; ++k) {
      fnp0 = __builtin_amdgcn_fdot2(u0.h2[k], u0.h2[k], fnp0, false);
      fnp1 = __builtin_amdgcn_fdot2(u1.h2[k], u1.h2[k], fnp1, false);
    }
#else
#pragma unroll
    for (int k = 0; k < 8; ++k) {
      float v0 = (float)u0.h[k], v1 = (float)u1.h[k];
      fnp0 += v0 * v0; fnp1 += v1 * v1;
    }
#endif
#pragma unroll
    for (int a = 0; a < 2; ++a) {
      half8 ah = epk[(ks * 16 + wave * 2 + a) * 64 + lane];
      acc[0][a] = __builtin_amdgcn_mfma_f32_32x32x16_f16(ah, u0.h, acc[0][a], 0, 0, 0);
      acc[1][a] = __builtin_amdgcn_mfma_f32_32x32x16_f16(ah, u1.h, acc[1][a], 0, 0, 0);
    }
  }
  fnp0 += __shfl_xor(fnp0, 32, 64);
  fnp1 += __shfl_xor(fnp1, 32, 64);

  int hi5 = lane >> 5;
#pragma unroll
  for (int bt = 0; bt < 2; ++bt) {
    float m1 = 3.4e38f, m2 = 3.4e38f; int i1 = 0;
#pragma unroll
    for (int a = 0; a < 2; ++a)
#pragma unroll
      for (int r = 0; r < 16; ++r) {
        int code = (wave * 2 + a) * 32 + (r & 3) + 8 * (r >> 2) + 4 * hi5;
        float v = senorm[code] - 2.0f * acc[bt][a][r];
        if (v < m1) { m2 = m1; m1 = v; i1 = code; }
        else if (v < m2) m2 = v;
      }
    float o1 = __shfl_xor(m1, 32, 64);
    float o2 = __shfl_xor(m2, 32, 64);
    int   oi = __shfl_xor(i1, 32, 64);
    float n2 = fminf(fmaxf(m1, o1), fminf(m2, o2));
    float n1 = fminf(m1, o1);
    int   ni = (o1 < m1) ? oi : i1;
    if (lane < 32) {
      int p = bt * 32 + lane;
      trim1[p * 8 + wave] = n1; trim2[p * 8 + wave] = n2; trii[p * 8 + wave] = ni;
    }
  }
  __syncthreads();

  if (wave == 0) {
    int p = lane;
    float m1 = trim1[p * 8], m2 = trim2[p * 8]; int i1 = trii[p * 8];
#pragma unroll
    for (int w = 1; w < 8; ++w) {
      float a1 = trim1[p * 8 + w], a2 = trim2[p * 8 + w]; int ai = trii[p * 8 + w];
      float n2 = fminf(fmaxf(m1, a1), fminf(m2, a2));
      if (a1 < m1) { m1 = a1; i1 = ai; }
      m2 = n2;
    }
    float myfn = (lane < 32) ? fnp0 : fnp1;
    int gpos = blk * 64 + p;
    tok[gpos] = i1;
    dst[gpos] = myfn + m1;
    fnv[gpos] = myfn;
    bool flag = (m2 - m1 < MARGIN);
    u64 mk = __ballot(flag);
    int base = 0;
    if (lane == 0 && mk) base = atomicAdd(wl, (int)__popcll(mk));
    base = __shfl(base, 0, 64);
    if (flag) {
      int off = (int)__popcll(mk & ((1ull << lane) - 1ull));
      wl[1 + base + off] = gpos;
    }
  }
}

// ---------------------------------------------------------------------------
// redo (round 9 verbatim — tok/dst only; no q to patch)
// ---------------------------------------------------------------------------
__global__ __launch_bounds__(256) void redo_kernel(
    const float* __restrict__ input, const float* __restrict__ embed,
    const float* __restrict__ enorm, const int* __restrict__ wl,
    int* __restrict__ tok, float* __restrict__ dst, const float* __restrict__ fnv) {
  __shared__ float sf[256], rv[256];
  __shared__ int   ri[256];
  int n = wl[0];
  int tid = threadIdx.x;
  for (int e = blockIdx.x; e < n; e += gridDim.x) {
    int gpos = wl[1 + e];
    int b = gpos >> 12, hw = gpos & 4095;
    sf[tid] = input[((size_t)(b * 256 + tid)) * 4096 + hw];
    __syncthreads();
    float d0 = 0.f, d1 = 0.f;
#pragma unroll 4
    for (int c = 0; c < 256; ++c) {
      float fv = sf[c];
      d0 += fv * embed[c * 512 + tid];
      d1 += fv * embed[c * 512 + 256 + tid];
    }
    float v0 = enorm[tid] - 2.f * d0;
    float v1 = enorm[256 + tid] - 2.f * d1;
    float bv; int bi;
    if (v1 < v0) { bv = v1; bi = 256 + tid; } else { bv = v0; bi = tid; }
    rv[tid] = bv; ri[tid] = bi;
    __syncthreads();
    for (int s = 128; s > 0; s >>= 1) {
      if (tid < s) {
        float ov = rv[tid + s]; int oi2 = ri[tid + s];
        if (ov < rv[tid] || (ov == rv[tid] && oi2 < ri[tid])) { rv[tid] = ov; ri[tid] = oi2; }
      }
      __syncthreads();
    }
    if (tid == 0) { tok[gpos] = ri[0]; dst[gpos] = fnv[gpos] + rv[0]; }
    __syncthreads();
  }
}

// ---------------------------------------------------------------------------
// finalize (slim): wordfreq atomics + diff reduction only.
// ---------------------------------------------------------------------------
__global__ __launch_bounds__(64) void finalize_kernel(
    const int* __restrict__ tok, const float* __restrict__ dst,
    float* __restrict__ wf, float* __restrict__ diffp) {
  int gbase = blockIdx.x * 64;
  int lane = threadIdx.x;
  int b = gbase >> 12;
  int t = tok[gbase + lane];
  atomicAdd(&wf[b * 512 + t], 1.0f / 4096.0f);
  float d = dst[gbase + lane];
#pragma unroll
  for (int off = 32; off >= 1; off >>= 1) d += __shfl_down(d, off, 64);
  if (lane == 0) atomicAdd(diffp, d);
}

// ---------------------------------------------------------------------------
// fused_layer0: v5 + XCD swizzle, but activations gathered from embedT via
// tok (no qin). Tokens staged once (100 ints, halo), interior used for the
// residual. Bit-identical data to materialized qA.
// ---------------------------------------------------------------------------
__global__ __launch_bounds__(512, 4) void fused_layer0(
    const int* __restrict__ tok, const ushort_t* __restrict__ embedT,
    ushort_t* __restrict__ qout,
    const ushort_t* __restrict__ w1pk, const float* __restrict__ b1,
    const ushort_t* __restrict__ w2pk, const float* __restrict__ b2) {
  __shared__ __align__(16) char arena[38912];
  ushort_t* hbuf   = (ushort_t*)arena;             // [64][76] = 9728 B
  float*    sb2    = (float*)(arena + 9728);       // 256 fl
  short8*   stg    = (short8*)(arena + 10752);     // 2 x 880 units (GEMM1)
  float*    red    = (float*)(arena + 10752);      // 4096 fl (K-reduce overlay)
  ushort_t* qstage = (ushort_t*)(arena + 10752);   // [64][136] (GEMM2 overlay)
  __shared__ int stok[100];

  int raw = blockIdx.x;
  int blk = (raw & 7) * 128 + (raw >> 3);          // T1 swizzle

  int b = blk >> 6; int t = blk & 63;
  int ty0 = (t >> 3) << 3;
  int tx0 = (t & 7) << 3;
  int tid = threadIdx.x, lane = tid & 63, w = tid >> 6;
  int pt = w & 1, ot = (w >> 1) & 1, kh = w >> 2;
  int l31 = lane & 31, kb5 = lane >> 5;

  if (tid < 256) sb2[tid] = b2[tid];
  if (tid >= 256 && tid < 356) {
    int u = tid - 256;
    int yy = u / 10, xx = u - yy * 10;
    int sy = ty0 + yy - 1, sx = tx0 + xx - 1;
    stok[u] = (sy >= 0 && sy < 64 && sx >= 0 && sx < 64)
            ? tok[b * 4096 + sy * 64 + sx] : -1;
  }
  __syncthreads();

  const short8* wp  = (const short8*)w1pk;         // layer 0
  const short8* w2p = (const short8*)w2pk;

  short8 sreg[2];
  auto loadch = [&](int cs) {
#pragma unroll
    for (int s = 0; s < 2; ++s) {
      int u = s * 512 + tid;
      if (u < 800) {
        int cg = u & 7; int pix = u >> 3;
        int tt = stok[pix];
        if (tt >= 0) {
          sreg[s] = *(const short8*)(embedT + (size_t)tt * 256 + cs * 64 + cg * 8);
        } else {
          short8 z;
#pragma unroll
          for (int k2 = 0; k2 < 8; ++k2) z[k2] = 0;
          sreg[s] = z;
        }
      }
    }
  };
  auto writech = [&](int buf) {
#pragma unroll
    for (int s = 0; s < 2; ++s) {
      int u = s * 512 + tid;
      if (u < 800) {
        int cg = u & 7; int pix = u >> 3; int y = pix / 10; int x = pix - y * 10;
        short8 sv = sreg[s];
#pragma unroll
        for (int k2 = 0; k2 < 8; ++k2) if (sv[k2] < 0) sv[k2] = 0;   // bf16 relu
        stg[buf * 880 + (y * 8 + cg) * 11 + x] = sv;
      }
    }
  };

  // ---- GEMM1: 4 chunks of 64 ch, K-split across kh ----
  f32x16 acc;
#pragma unroll
  for (int r = 0; r < 16; ++r) acc[r] = 0.f;

  int py0 = pt * 4 + (l31 >> 3);
  int px0 = lane & 7;

  loadch(0);
  writech(0);
#pragma unroll 1
  for (int cs = 0; cs < 4; ++cs) {
    __syncthreads();
    if (cs < 3) loadch(cs + 1);
    int buf = cs & 1;
#pragma unroll 1
    for (int dy = 0; dy < 3; ++dy) {
#pragma unroll 1
      for (int dx = 0; dx < 3; ++dx) {
        int tap = dy * 3 + dx;
#pragma unroll
        for (int ks2 = 0; ks2 < 2; ++ks2) {
          int kk = kh * 2 + ks2;
          short8 A = stg[buf * 880 + ((py0 + dy) * 8 + kk * 2 + kb5) * 11 + px0 + dx];
          short8 B = wp[(tap * 16 + cs * 4 + kk) * 128 + ot * 64 + lane];
          acc = __builtin_amdgcn_mfma_f32_32x32x16_bf16(A, B, acc, 0, 0, 0);
        }
      }
    }
    if (cs < 3) writech((cs + 1) & 1);
  }
  __syncthreads();

  // ---- K-reduce ----
  if (kh == 1) {
    float4* d = (float4*)(red + (w & 3) * 1024 + lane * 16);
#pragma unroll
    for (int r4 = 0; r4 < 4; ++r4) {
      float4 v; v.x = acc[r4 * 4]; v.y = acc[r4 * 4 + 1];
      v.z = acc[r4 * 4 + 2]; v.w = acc[r4 * 4 + 3];
      d[r4] = v;
    }
  }
  __syncthreads();
  if (kh == 0) {
    const float* s = red + (w & 3) * 1024 + lane * 16;
    int oc = ot * 32 + l31;
    float bb = b1[oc];
#pragma unroll
    for (int r = 0; r < 16; ++r) {
      int row = (r & 3) + 8 * (r >> 2) + 4 * kb5;
      hbuf[(pt * 32 + row) * 76 + oc] = f2bf(fmaxf(acc[r] + s[r] + bb, 0.f));
    }
  }
  __syncthreads();

  // ---- GEMM2 + residual (residual gathered from embedT via stok) ----
  int pt2 = w & 1, coq = w >> 1;
#pragma unroll 1
  for (int ch = 0; ch < 2; ++ch) {
    short8 qv[2];
#pragma unroll
    for (int it = 0; it < 2; ++it) {
      int u = it * 512 + tid;
      int p = u >> 4, c8 = u & 15;
      int tt = stok[((p >> 3) + 1) * 10 + (p & 7) + 1];   // interior: always >= 0
      qv[it] = *(const short8*)(embedT + (size_t)tt * 256 + ch * 128 + c8 * 8);
    }

    f32x16 acc2;
#pragma unroll
    for (int r = 0; r < 16; ++r) acc2[r] = 0.f;
#pragma unroll
    for (int ks = 0; ks < 4; ++ks) {
      short8 A = *(const short8*)(hbuf + (pt2 * 32 + l31) * 76 + ks * 16 + kb5 * 8);
      short8 B = w2p[(ks * 8 + ch * 4 + coq) * 64 + lane];
      acc2 = __builtin_amdgcn_mfma_f32_32x32x16_bf16(A, B, acc2, 0, 0, 0);
    }
    {
      int cc = coq * 32 + l31;
      float bb2 = sb2[ch * 128 + cc];
#pragma unroll
      for (int r = 0; r < 16; ++r) {
        int row = (r & 3) + 8 * (r >> 2) + 4 * kb5;
        qstage[(pt2 * 32 + row) * 136 + cc] = f2bf(acc2[r] + bb2);
      }
    }
    __syncthreads();
#pragma unroll
    for (int it = 0; it < 2; ++it) {
      int u = it * 512 + tid;
      int p = u >> 4, c8 = u & 15;
      short8 hv = *(const short8*)(qstage + p * 136 + c8 * 8);
      int gy = ty0 + (p >> 3), gx = tx0 + (p & 7);
      size_t gidx = ((size_t)(b * 4096 + gy * 64 + gx)) * 256 + ch * 128 + c8 * 8;
      short8 ov;
#pragma unroll
      for (int k2 = 0; k2 < 8; ++k2)
        ov[k2] = (short)f2bf(bf2f((ushort_t)qv[it][k2]) + bf2f((ushort_t)hv[k2]));
      *(short8*)(qout + gidx) = ov;
    }
    __syncthreads();
  }
}

// ---------------------------------------------------------------------------
// fused residual layer v5 + T1 XCD swizzle (round 15 verbatim — layers 1,2).
// ---------------------------------------------------------------------------
__global__ __launch_bounds__(512, 4) void fused_layer(
    const ushort_t* __restrict__ qin, ushort_t* __restrict__ qout,
    const ushort_t* __restrict__ w1pk, const float* __restrict__ b1,
    const ushort_t* __restrict__ w2pk, const float* __restrict__ b2, int l) {
  __shared__ __align__(16) char arena[38912];
  ushort_t* hbuf   = (ushort_t*)arena;             // [64][76] = 9728 B
  float*    sb2    = (float*)(arena + 9728);       // 256 fl
  short8*   stg    = (short8*)(arena + 10752);     // 2 x 880 units (GEMM1)
  float*    red    = (float*)(arena + 10752);      // 4096 fl (K-reduce overlay)
  ushort_t* qstage = (ushort_t*)(arena + 10752);   // [64][136] (GEMM2 overlay)

  int raw = blockIdx.x;
  int blk = (raw & 7) * 128 + (raw >> 3);          // T1 swizzle

  int b = blk >> 6; int t = blk & 63;
  int ty0 = (t >> 3) << 3;
  int tx0 = (t & 7) << 3;
  int tid = threadIdx.x, lane = tid & 63, w = tid >> 6;
  int pt = w & 1, ot = (w >> 1) & 1, kh = w >> 2;
  int l31 = lane & 31, kb5 = lane >> 5;

  if (tid < 256) sb2[tid] = b2[l * 256 + tid];

  const short8* wp  = (const short8*)w1pk + (size_t)l * 18432;
  const short8* w2p = (const short8*)w2pk;

  short8 sreg[2];
  auto loadch = [&](int cs) {
#pragma unroll
    for (int s = 0; s < 2; ++s) {
      int u = s * 512 + tid;
      if (u < 800) {
        int cg = u & 7; int pix = u >> 3; int y = pix / 10; int x = pix - y * 10;
        int sy = ty0 + y - 1, sx = tx0 + x - 1;
        if (sy >= 0 && sy < 64 && sx >= 0 && sx < 64) {
          sreg[s] = *(const short8*)(qin + ((size_t)(b * 4096 + sy * 64 + sx)) * 256 + cs * 64 + cg * 8);
        } else {
          short8 z;
#pragma unroll
          for (int k2 = 0; k2 < 8; ++k2) z[k2] = 0;
          sreg[s] = z;
        }
      }
    }
  };
  auto writech = [&](int buf) {
#pragma unroll
    for (int s = 0; s < 2; ++s) {
      int u = s * 512 + tid;
      if (u < 800) {
        int cg = u & 7; int pix = u >> 3; int y = pix / 10; int x = pix - y * 10;
        short8 sv = sreg[s];
#pragma unroll
        for (int k2 = 0; k2 < 8; ++k2) if (sv[k2] < 0) sv[k2] = 0;   // bf16 relu
        stg[buf * 880 + (y * 8 + cg) * 11 + x] = sv;
      }
    }
  };

  // ---- GEMM1: 4 chunks of 64 ch, K-split across kh ----
  f32x16 acc;
#pragma unroll
  for (int r = 0; r < 16; ++r) acc[r] = 0.f;

  int py0 = pt * 4 + (l31 >> 3);
  int px0 = lane & 7;

  loadch(0);
  writech(0);
#pragma unroll 1
  for (int cs = 0; cs < 4; ++cs) {
    __syncthreads();                      // buf[cs&1] writes visible
    if (cs < 3) loadch(cs + 1);           // issue loads; hidden by MFMAs
    int buf = cs & 1;
#pragma unroll 1
    for (int dy = 0; dy < 3; ++dy) {
#pragma unroll 1
      for (int dx = 0; dx < 3; ++dx) {
        int tap = dy * 3 + dx;
#pragma unroll
        for (int ks2 = 0; ks2 < 2; ++ks2) {
          int kk = kh * 2 + ks2;          // k16 within chunk
          short8 A = stg[buf * 880 + ((py0 + dy) * 8 + kk * 2 + kb5) * 11 + px0 + dx];
          short8 B = wp[(tap * 16 + cs * 4 + kk) * 128 + ot * 64 + lane];
          acc = __builtin_amdgcn_mfma_f32_32x32x16_bf16(A, B, acc, 0, 0, 0);
        }
      }
    }
    if (cs < 3) writech((cs + 1) & 1);    // write late
  }
  __syncthreads();

  // ---- K-reduce: kh=1 partials through LDS, kh=0 combines -> hbuf ----
  if (kh == 1) {
    float4* d = (float4*)(red + (w & 3) * 1024 + lane * 16);
#pragma unroll
    for (int r4 = 0; r4 < 4; ++r4) {
      float4 v; v.x = acc[r4 * 4]; v.y = acc[r4 * 4 + 1];
      v.z = acc[r4 * 4 + 2]; v.w = acc[r4 * 4 + 3];
      d[r4] = v;
    }
  }
  __syncthreads();
  if (kh == 0) {
    const float* s = red + (w & 3) * 1024 + lane * 16;
    int oc = ot * 32 + l31;
    float bb = b1[l * 64 + oc];
#pragma unroll
    for (int r = 0; r < 16; ++r) {
      int row = (r & 3) + 8 * (r >> 2) + 4 * kb5;
      hbuf[(pt * 32 + row) * 76 + oc] = f2bf(fmaxf(acc[r] + s[r] + bb, 0.f));
    }
  }
  __syncthreads();

  // ---- GEMM2: wave = (pt2, coq); 2 co-halves through qstage ----
  int pt2 = w & 1, coq = w >> 1;          // coq 0..3
#pragma unroll 1
  for (int ch = 0; ch < 2; ++ch) {
    short8 qv[2];
#pragma unroll
    for (int it = 0; it < 2; ++it) {
      int u = it * 512 + tid;
      int p = u >> 4, c8 = u & 15;
      int gy = ty0 + (p >> 3), gx = tx0 + (p & 7);
      qv[it] = *(const short8*)(qin + ((size_t)(b * 4096 + gy * 64 + gx)) * 256 + ch * 128 + c8 * 8);
    }

    f32x16 acc2;
#pragma unroll
    for (int r = 0; r < 16; ++r) acc2[r] = 0.f;
#pragma unroll
    for (int ks = 0; ks < 4; ++ks) {
      short8 A = *(const short8*)(hbuf + (pt2 * 32 + l31) * 76 + ks * 16 + kb5 * 8);
      short8 B = w2p[((l * 4 + ks) * 8 + ch * 4 + coq) * 64 + lane];
      acc2 = __builtin_amdgcn_mfma_f32_32x32x16_bf16(A, B, acc2, 0, 0, 0);
    }
    {
      int cc = coq * 32 + l31;
      float bb2 = sb2[ch * 128 + cc];
#pragma unroll
      for (int r = 0; r < 16; ++r) {
        int row = (r & 3) + 8 * (r >> 2) + 4 * kb5;
        qstage[(pt2 * 32 + row) * 136 + cc] = f2bf(acc2[r] + bb2);
      }
    }
    __syncthreads();
#pragma unroll
    for (int it = 0; it < 2; ++it) {
      int u = it * 512 + tid;
      int p = u >> 4, c8 = u & 15;
      short8 hv = *(const short8*)(qstage + p * 136 + c8 * 8);
      int gy = ty0 + (p >> 3), gx = tx0 + (p & 7);
      size_t gidx = ((size_t)(b * 4096 + gy * 64 + gx)) * 256 + ch * 128 + c8 * 8;
      short8 ov;
#pragma unroll
      for (int k2 = 0; k2 < 8; ++k2)
        ov[k2] = (short)f2bf(bf2f((ushort_t)qv[it][k2]) + bf2f((ushort_t)hv[k2]));
      *(short8*)(qout + gidx) = ov;
    }
    __syncthreads();
  }
}

// ---------------------------------------------------------------------------
// final 1x1 head (unchanged)
// ---------------------------------------------------------------------------
__global__ __launch_bounds__(256) void final_kernel(
    const ushort_t* __restrict__ qbuf, const float* __restrict__ ow,
    const float* __restrict__ ob, float* __restrict__ out,
    const float* __restrict__ ws) {
  int t = blockIdx.x * 256 + threadIdx.x;
  int pos = t >> 4, c16 = t & 15;
  const ushort_t* qp = qbuf + (size_t)pos * 256 + c16 * 16;
  short8 v0 = *(const short8*)qp;
  short8 v1 = *(const short8*)(qp + 8);
  float a0 = 0.f, a1 = 0.f, a2 = 0.f;
#pragma unroll
  for (int k = 0; k < 16; ++k) {
    float f = bf2f((ushort_t)(k < 8 ? v0[k] : v1[k - 8]));
    int c = c16 * 16 + k;
    a0 += f * ow[c];
    a1 += f * ow[256 + c];
    a2 += f * ow[512 + c];
  }
#pragma unroll
  for (int off = 1; off < 16; off <<= 1) {
    a0 += __shfl_xor(a0, off, 64);
    a1 += __shfl_xor(a1, off, 64);
    a2 += __shfl_xor(a2, off, 64);
  }
  if (c16 == 0) {
    int b = pos >> 12, hw = pos & 4095;
    out[(b * 3 + 0) * 4096 + hw] = a0 + ob[0];
    out[(b * 3 + 1) * 4096 + hw] = a1 + ob[1];
    out[(b * 3 + 2) * 4096 + hw] = a2 + ob[2];
  }
  if (t == 0) out[196608] = ws[WS_DIFF] * (1.0f / 16777216.0f);
}

// ---------------------------------------------------------------------------
extern "C" void kernel_launch(void* const* d_in, const int* in_sizes, int n_in,
                              void* d_out, int out_size, void* d_ws, size_t ws_size,
                              hipStream_t stream) {
  (void)in_sizes; (void)n_in; (void)out_size; (void)ws_size;
  const float* input = (const float*)d_in[0];
  const float* embed = (const float*)d_in[1];
  const float* b1 = (const float*)d_in[3];
  const float* b2 = (const float*)d_in[5];
  const float* ow = (const float*)d_in[6];
  const float* ob = (const float*)d_in[7];
  float* ws = (float*)d_ws;
  float* out = (float*)d_out;
  float* wf = out + 196609;

  ushort_t* qA = (ushort_t*)(ws + WS_QA);
  ushort_t* qB = (ushort_t*)(ws + WS_QB);
  const ushort_t* et = (const ushort_t*)(ws + WS_ET);
  const half8* epk = (const half8*)(ws + WS_EPK);
  const ushort_t* w1pk = (const ushort_t*)(ws + WS_W1PK);
  const ushort_t* w2pk = (const ushort_t*)(ws + WS_W2PK);
  int*   tok = (int*)(ws + WS_TOK);
  float* dst = ws + WS_DST;
  float* fnv = ws + WS_FN;
  int*   wl  = (int*)(ws + WS_WL);

  hipLaunchKernelGGL(prep_kernel, dim3(1728), dim3(256), 0, stream,
                     embed, (const float*)d_in[2], (const float*)d_in[4], ws, wf);
  hipLaunchKernelGGL(dist_kernel, dim3(1024), dim3(512), 0, stream,
                     input, epk, ws + WS_EN, tok, dst, fnv, wl);
  hipLaunchKernelGGL(redo_kernel, dim3(1024), dim3(256), 0, stream,
                     input, embed, ws + WS_EN, wl, tok, dst, fnv);
  hipLaunchKernelGGL(finalize_kernel, dim3(1024), dim3(64), 0, stream,
                     tok, dst, wf, ws + WS_DIFF);
  hipLaunchKernelGGL(fused_layer0, dim3(1024), dim3(512), 0, stream,
                     tok, et, qB, w1pk, b1, w2pk, b2);
  hipLaunchKernelGGL(fused_layer, dim3(1024), dim3(512), 0, stream,
                     qB, qA, w1pk, b1, w2pk, b2, 1);
  hipLaunchKernelGGL(fused_layer, dim3(1024), dim3(512), 0, stream,
                     qA, qB, w1pk, b1, w2pk, b2, 2);
  hipLaunchKernelGGL(final_kernel, dim3(4096), dim3(256), 0, stream,
                     qB, ow, ob, out, ws);
}